// Round 5
// baseline (5665.746 us; speedup 1.0000x reference)
//
#include <hip/hip_runtime.h>

#define TT 4096
#define BB 64
#define RR 16
#define OUT_HID (BB*TT)

#define SYS_LDU(p)    __hip_atomic_load((p),      __ATOMIC_RELAXED, __HIP_MEMORY_SCOPE_SYSTEM)
#define SYS_STU(p,v)  __hip_atomic_store((p),(v), __ATOMIC_RELAXED, __HIP_MEMORY_SCOPE_SYSTEM)
#define SYS_STF(p,v)  __hip_atomic_store((p),(v), __ATOMIC_RELAXED, __HIP_MEMORY_SCOPE_SYSTEM)

__device__ __forceinline__ float sigm(float x) {
    return __builtin_amdgcn_rcpf(1.0f + __expf(-x));
}
__device__ __forceinline__ float tanhfast(float x) {
    return 1.0f - 2.0f * __builtin_amdgcn_rcpf(1.0f + __expf(2.0f * x));
}

#define FMA4(acc, wv, hv)                                            \
    acc = fmaf((wv).x, (hv).x, acc); acc = fmaf((wv).y, (hv).y, acc); \
    acc = fmaf((wv).z, (hv).z, acc); acc = fmaf((wv).w, (hv).w, acc);

#define X8(M) M(0) M(1) M(2) M(3) M(4) M(5) M(6) M(7)

#define DECLW(i) float4 wA##i, wB##i, wC##i;
#define LDW(i)   wA##i = *(const float4*)(rpA + 16*(i)); \
                 wB##i = *(const float4*)(rpB + 16*(i)); \
                 wC##i = *(const float4*)(rpC + 16*(i));
// Pin one float4 via 4 scalar "+v" constraints (single-reg ties ARE supported).
// The vector's value becomes asm-produced -> the weight load cannot be
// rematerialized inside the loop; weights stay VGPR-resident.
#define PIN1(vv) { float _t0 = (vv).x, _t1 = (vv).y, _t2 = (vv).z, _t3 = (vv).w; \
    asm volatile("" : "+v"(_t0), "+v"(_t1), "+v"(_t2), "+v"(_t3));              \
    (vv).x = _t0; (vv).y = _t1; (vv).z = _t2; (vv).w = _t3; }
#define PINW(i)  PIN1(wA##i) PIN1(wB##i) PIN1(wC##i)
#define DECLY(i) float4 y##i;
#define GEMV_LDS(i) { float4 hv_ = hb4[4*(i) + c]; \
    FMA4(a0, wA##i, hv_); FMA4(a1, wB##i, hv_); FMA4(a2, wC##i, hv_); }
#define GEMV_Y(i) { FMA4(a0, wA##i, y##i); FMA4(a1, wB##i, y##i); FMA4(a2, wC##i, y##i); }

#define RED3() \
    float A0 = a0 + __shfl_xor(a0, 1); A0 += __shfl_xor(A0, 2); \
    float A1 = a1 + __shfl_xor(a1, 1); A1 += __shfl_xor(A1, 2); \
    float A2 = a2 + __shfl_xor(a2, 1); A2 += __shfl_xor(A2, 2);

// Roles: 0 = L0 recurrence, 1 = L1 x-GEMV (even t), 2 = L1 x-GEMV (odd t),
// 3 = L1 recurrence + fc.  256 blocks = 256 CUs, all co-resident.
// Ring handoff: system-scope relaxed (sc0 sc1) data+flags meeting at L3;
// producer orders data-before-flag via __syncthreads()'s vmcnt(0) drain.
__global__ __launch_bounds__(512, 2) void gru_pipe(
    const float* __restrict__ data,   const float* __restrict__ hidden,
    const float* __restrict__ w_ih0,  const float* __restrict__ w_hh0,
    const float* __restrict__ b_ih0,  const float* __restrict__ b_hh0,
    const float* __restrict__ w_ih1,  const float* __restrict__ w_hh1,
    const float* __restrict__ b_ih1,  const float* __restrict__ b_hh1,
    const float* __restrict__ fc_w,   const float* __restrict__ fc_b,
    float* __restrict__ out, float* __restrict__ wsf)
{
    const int bid  = blockIdx.x;
    const int role = bid >> 6;
    const int b    = bid & 63;
    const int tid  = threadIdx.x;
    const int u    = tid >> 2;      // hidden unit 0..127
    const int c    = tid & 3;       // k-chunk lane in the 4-lane group

    float* y0r = wsf;                               // [BB][RR][128]
    float* xgr = wsf + BB*RR*128;                   // [BB][RR][384]
    unsigned* fl   = (unsigned*)(wsf + BB*RR*128 + BB*RR*384);
    unsigned* yflag = fl + 0*BB*RR + b*RR;
    unsigned* ycons = fl + 1*BB*RR + b*RR;
    unsigned* xflag = fl + 2*BB*RR + b*RR;
    unsigned* xcons = fl + 3*BB*RR + b*RR;

    __shared__ __align__(16) float hs[128];
    __shared__ float xs[TT];                        // role-0 input stage (16 KB)

    if (role == 0) {
        // ----------------------------- L0 recurrence -----------------------------
        X8(DECLW)
        { const float* rpA = w_hh0 + u*128 + 4*c;
          const float* rpB = rpA + 16384; const float* rpC = rpA + 32768;
          X8(LDW) }
        X8(PINW)
        const float br  = b_ih0[u]       + b_hh0[u];
        const float bz  = b_ih0[u + 128] + b_hh0[u + 128];
        const float bin = b_ih0[u + 256];
        const float bhn = b_hh0[u + 256];
        const float wir = w_ih0[u], wiz = w_ih0[u + 128], win = w_ih0[u + 256];

        float hold = hidden[b*128 + u];
        if (tid < 128) hs[tid] = hidden[b*128 + tid];
        { const float* xp = data + (size_t)b*TT;
          for (int i = tid; i < TT; i += 512) xs[i] = xp[i]; }
        __syncthreads();

        const float4* hb4 = (const float4*)hs;
        float* yr = y0r + (size_t)b*RR*128;
        unsigned g = 0;

        for (int t = 0; t < TT; ++t) {
            const int s = t & (RR - 1);
            if (tid == 0 && t >= RR) {              // barrier below gates the others
                while (g != (unsigned)(t - RR + 1)) {
                    __builtin_amdgcn_s_sleep(1); g = SYS_LDU(&ycons[s]);
                }
            }
            const float xv = xs[t];
            float a0 = 0.f, a1 = 0.f, a2 = 0.f;
            X8(GEMV_LDS)
            RED3()
            const float r = sigm(fmaf(xv, wir, A0 + br));
            const float z = sigm(fmaf(xv, wiz, A1 + bz));
            const float n = tanhfast(fmaf(r, A2 + bhn, fmaf(xv, win, bin)));
            const float hnew = fmaf(z, hold - n, n);
            __syncthreads();                         // readers done + poll joined
            if (c == 0) { hs[u] = hnew; SYS_STF(&yr[s*128 + u], hnew); }
            __syncthreads();                         // drains vmcnt: y0 at L3
            if (tid == 0) SYS_STU(&yflag[s], (unsigned)(t + 1));
            if (t + 1 >= RR) g = SYS_LDU(&ycons[(t + 1) & (RR - 1)]);  // prefetch
            hold = hnew;
        }
        if (tid < 128) out[OUT_HID + b*128 + tid] = hs[tid];

    } else if (role <= 2) {
        // --------------- L1 x-side GEMV, split by timestep parity ---------------
        X8(DECLW)
        { const float* rpA = w_ih1 + u*128 + 4*c;
          const float* rpB = rpA + 16384; const float* rpC = rpA + 32768;
          X8(LDW) }
        X8(PINW)
        X8(DECLY)
        const int par = role - 1;
        float* xg = xgr + (size_t)b*RR*384;
        const float* yrd = y0r + (size_t)b*RR*128;

        unsigned fy = SYS_LDU(&yflag[par & (RR - 1)]);   // prefetched flag values
        unsigned fx = 0;

        for (int t = par; t < TT; t += 2) {
            const int s = t & (RR - 1);
            // all threads self-guard (no entry barrier needed)
            while (fy != (unsigned)(t + 1)) { __builtin_amdgcn_s_sleep(1); fy = SYS_LDU(&yflag[s]); }
            if (t >= RR)
                while (fx != (unsigned)(t - RR + 1)) { __builtin_amdgcn_s_sleep(1); fx = SYS_LDU(&xcons[s]); }
            const float4* yb = (const float4*)(yrd + s*128 + 4*c);
            asm volatile(
                "global_load_dwordx4 %0, %8, off sc0 sc1\n\t"
                "global_load_dwordx4 %1, %8, off offset:64 sc0 sc1\n\t"
                "global_load_dwordx4 %2, %8, off offset:128 sc0 sc1\n\t"
                "global_load_dwordx4 %3, %8, off offset:192 sc0 sc1\n\t"
                "global_load_dwordx4 %4, %8, off offset:256 sc0 sc1\n\t"
                "global_load_dwordx4 %5, %8, off offset:320 sc0 sc1\n\t"
                "global_load_dwordx4 %6, %8, off offset:384 sc0 sc1\n\t"
                "global_load_dwordx4 %7, %8, off offset:448 sc0 sc1\n\t"
                "s_waitcnt vmcnt(0)"
                : "=&v"(y0), "=&v"(y1), "=&v"(y2), "=&v"(y3),
                  "=&v"(y4), "=&v"(y5), "=&v"(y6), "=&v"(y7)
                : "v"(yb) : "memory");
            // prefetch flags for the next handled step (t+2); latency hides
            // under the GEMV + store + barrier (~600 cy)
            fy = SYS_LDU(&yflag[(t + 2) & (RR - 1)]);
            fx = SYS_LDU(&xcons[(t + 2) & (RR - 1)]);
            float a0 = 0.f, a1 = 0.f, a2 = 0.f;
            X8(GEMV_Y)
            RED3()
            if (c == 0) {
                SYS_STF(&xg[s*384 + u],       A0);
                SYS_STF(&xg[s*384 + 128 + u], A1);
                SYS_STF(&xg[s*384 + 256 + u], A2);
            }
            __syncthreads();                         // drains vmcnt: xg at L3
            if (tid == 0) {
                SYS_STU(&xflag[s], (unsigned)(t + 1));
                SYS_STU(&ycons[s], (unsigned)(t + 1));
            }
        }

    } else {
        // ------------------------ L1 recurrence + fc head ------------------------
        X8(DECLW)
        { const float* rpA = w_hh1 + u*128 + 4*c;
          const float* rpB = rpA + 16384; const float* rpC = rpA + 32768;
          X8(LDW) }
        X8(PINW)
        const float br  = b_ih1[u]       + b_hh1[u];
        const float bz  = b_ih1[u + 128] + b_hh1[u + 128];
        const float bin = b_ih1[u + 256];
        const float bhn = b_hh1[u + 256];
        float fw0 = 0.f, fw1 = 0.f, fb = 0.f;
        if (tid < 64) { fw0 = fc_w[tid]; fw1 = fc_w[tid + 64]; fb = fc_b[0]; }

        float hold = hidden[8192 + b*128 + u];
        if (tid < 128) hs[tid] = hidden[8192 + b*128 + tid];
        __syncthreads();

        const float4* hb4 = (const float4*)hs;
        const float* xgd = xgr + (size_t)b*RR*384;
        float* outp = out + (size_t)b*TT;
        unsigned f = SYS_LDU(&xflag[0]);

        for (int t = 0; t < TT; ++t) {
            const int s = t & (RR - 1);
            while (f != (unsigned)(t + 1)) { __builtin_amdgcn_s_sleep(1); f = SYS_LDU(&xflag[s]); }
            const float* xgp = xgd + s*384 + u;
            float xr, xz, xn;
            asm volatile(                            // issue-early, wait-late
                "global_load_dword %0, %3, off sc0 sc1\n\t"
                "global_load_dword %1, %3, off offset:512 sc0 sc1\n\t"
                "global_load_dword %2, %3, off offset:1024 sc0 sc1"
                : "=&v"(xr), "=&v"(xz), "=&v"(xn) : "v"(xgp) : "memory");
            if (t + 1 < TT) f = SYS_LDU(&xflag[(t + 1) & (RR - 1)]);   // prefetch poll
            float fcv = 0.f;
            if (tid < 64 && t >= 1)
                fcv = fmaxf(hs[tid], 0.f)*fw0 + fmaxf(hs[tid + 64], 0.f)*fw1;
            float a0 = 0.f, a1 = 0.f, a2 = 0.f;
            X8(GEMV_LDS)                             // xg latency hides under this
            RED3()
            asm volatile("s_waitcnt vmcnt(0)" : "+v"(xr), "+v"(xz), "+v"(xn));
            const float r = sigm(xr + A0 + br);
            const float z = sigm(xz + A1 + bz);
            const float n = tanhfast(fmaf(r, A2 + bhn, xn + bin));
            const float hnew = fmaf(z, hold - n, n);
            if (tid < 64 && t >= 1) {
#pragma unroll
                for (int off = 1; off < 64; off <<= 1) fcv += __shfl_xor(fcv, off);
                if (tid == 0) outp[t - 1] = fcv + fb;
            }
            __syncthreads();
            if (c == 0) hs[u] = hnew;
            __syncthreads();
            if (tid == 0) SYS_STU(&xcons[s], (unsigned)(t + 1));
            hold = hnew;
        }
        float fcv = 0.f;
        if (tid < 64) {
            fcv = fmaxf(hs[tid], 0.f)*fw0 + fmaxf(hs[tid + 64], 0.f)*fw1;
#pragma unroll
            for (int off = 1; off < 64; off <<= 1) fcv += __shfl_xor(fcv, off);
            if (tid == 0) outp[TT - 1] = fcv + fb;
        }
        if (tid < 128) out[OUT_HID + 8192 + b*128 + tid] = hs[tid];
    }
}

extern "C" void kernel_launch(void* const* d_in, const int* in_sizes, int n_in,
                              void* d_out, int out_size, void* d_ws, size_t ws_size,
                              hipStream_t stream) {
    (void)in_sizes; (void)n_in; (void)out_size; (void)ws_size;
    gru_pipe<<<256, 512, 0, stream>>>(
        (const float*)d_in[0],  (const float*)d_in[1],
        (const float*)d_in[2],  (const float*)d_in[3],
        (const float*)d_in[4],  (const float*)d_in[5],
        (const float*)d_in[6],  (const float*)d_in[7],
        (const float*)d_in[8],  (const float*)d_in[9],
        (const float*)d_in[10], (const float*)d_in[11],
        (float*)d_out, (float*)d_ws);
}